// Round 1
// baseline (108.171 us; speedup 1.0000x reference)
//
#include <hip/hip_runtime.h>
#include <hip/hip_bf16.h>

typedef __attribute__((ext_vector_type(8))) short bf16x8;
typedef __attribute__((ext_vector_type(4))) float f32x4;
typedef __attribute__((ext_vector_type(4))) unsigned short u16x4;

#define MFMA16(a, b, c) __builtin_amdgcn_mfma_f32_16x16x32_bf16((a), (b), (c), 0, 0, 0)

#define WQT_ELEMS 27648   // 288*96
#define WPT_ELEMS 9216    // 96*96

__device__ __forceinline__ unsigned short f2bf(float f) {
    union { float f; unsigned u; } v; v.f = f;
    return (unsigned short)((v.u + 0x7FFFu + ((v.u >> 16) & 1u)) >> 16);
}

// Transpose+convert weights: wqT[j][c] = w_qkv[c][j] (bf16), wpT[j][c] = w_proj[c][j]
__global__ void wconv_kernel(const float* __restrict__ wqkv,
                             const float* __restrict__ wproj,
                             unsigned short* __restrict__ wsT) {
    int o = blockIdx.x * 256 + threadIdx.x;
    if (o < WQT_ELEMS) {
        int j = o / 96, c = o % 96;
        wsT[o] = f2bf(wqkv[c * 288 + j]);
    } else if (o < WQT_ELEMS + WPT_ELEMS) {
        int o2 = o - WQT_ELEMS;
        int j = o2 / 96, c = o2 % 96;
        wsT[o] = f2bf(wproj[c * 96 + j]);
    }
}

// One block per window. 256 threads = 4 waves. Wave wv owns token rows [16wv,16wv+16).
__global__ __launch_bounds__(256, 2)
void winattn_kernel(const float* __restrict__ x,
                    const unsigned short* __restrict__ wsT,
                    const float* __restrict__ bproj,
                    float* __restrict__ out) {
    // LDS: total 65024 bytes
    __shared__ unsigned short xs[64 * 96];       // window input bf16; later reused as merged O
    __shared__ unsigned short qs[64 * 96];       // q  [t][j], tight (pad overflow hits zeroed k-pads)
    __shared__ unsigned short ks[64 * 136];      // k  [t][hd*32 + kk], kk 24..31 zeroed
    __shared__ unsigned short vt[4 * 24 * 72];   // v^T [hd][c][u], u-dim padded to 72
    __shared__ unsigned short ps[64 * 72];       // softmax probs [t][u]

    const int tid = threadIdx.x;
    const int lane = tid & 63;
    const int wv = tid >> 6;        // wave id = m-band
    const int p  = lane & 15;
    const int qg = lane >> 4;

    const int iw  = blockIdx.x;
    const int l_i = iw & 31;
    const int m_i = (iw >> 5) & 15;
    const int n_i = iw >> 9;

    const f32x4 fzero = {0.f, 0.f, 0.f, 0.f};

    // ---------- phase 1: stage x window -> LDS (bf16) ----------
    #pragma unroll
    for (int it = 0; it < 6; ++it) {
        int slot = tid + it * 256;            // 64 tokens * 24 float4 slots
        int t = slot / 24, cq = slot % 24;
        int td = t >> 4, th = (t >> 2) & 3, tw = t & 3;
        int off = (((n_i * 4 + td) * 64 + (m_i * 4 + th)) * 128 + (l_i * 4 + tw)) * 96 + cq * 4;
        float4 v4 = *reinterpret_cast<const float4*>(x + off);
        u16x4 h;
        h[0] = f2bf(v4.x); h[1] = f2bf(v4.y); h[2] = f2bf(v4.z); h[3] = f2bf(v4.w);
        *reinterpret_cast<u16x4*>(&xs[t * 96 + cq * 4]) = h;
    }
    // zero the k head-padding (kk = 24..31 for each head, every token)
    {
        int u = tid >> 2, hd = tid & 3;
        bf16x8 z = {0, 0, 0, 0, 0, 0, 0, 0};
        *reinterpret_cast<bf16x8*>(&ks[u * 136 + hd * 32 + 24]) = z;
    }
    __syncthreads();

    // ---------- phase 2: QKV GEMM  qkv[64][288] = xs[64][96] @ wq[96][288] ----------
    // waves split the 18 n-tiles; every B tile of wqT is fetched once per block.
    bf16x8 afr[4][3];
    #pragma unroll
    for (int mt = 0; mt < 4; ++mt)
        #pragma unroll
        for (int kt = 0; kt < 3; ++kt)
            afr[mt][kt] = *reinterpret_cast<const bf16x8*>(&xs[(mt * 16 + p) * 96 + kt * 32 + qg * 8]);

    for (int i = 0; i < 5; ++i) {
        int nt = wv + i * 4;
        if (nt >= 18) break;                  // wave-uniform
        f32x4 acc[4];
        #pragma unroll
        for (int mt = 0; mt < 4; ++mt) acc[mt] = fzero;
        #pragma unroll
        for (int kt = 0; kt < 3; ++kt) {
            bf16x8 bfr = *reinterpret_cast<const bf16x8*>(&wsT[(nt * 16 + p) * 96 + kt * 32 + qg * 8]);
            #pragma unroll
            for (int mt = 0; mt < 4; ++mt)
                acc[mt] = MFMA16(afr[mt][kt], bfr, acc[mt]);
        }
        int jcol = nt * 16 + p;               // output column (D: col = lane&15)
        if (jcol < 96) {                      // q
            #pragma unroll
            for (int mt = 0; mt < 4; ++mt)
                #pragma unroll
                for (int rg = 0; rg < 4; ++rg)
                    qs[(mt * 16 + qg * 4 + rg) * 96 + jcol] = f2bf(acc[mt][rg]);
        } else if (jcol < 192) {              // k
            int jk = jcol - 96;
            int hd = jk / 24, kk = jk % 24;
            #pragma unroll
            for (int mt = 0; mt < 4; ++mt)
                #pragma unroll
                for (int rg = 0; rg < 4; ++rg)
                    ks[(mt * 16 + qg * 4 + rg) * 136 + hd * 32 + kk] = f2bf(acc[mt][rg]);
        } else {                              // v (transposed store)
            int jv = jcol - 192;
            int hd = jv / 24, cc = jv % 24;
            #pragma unroll
            for (int mt = 0; mt < 4; ++mt)
                #pragma unroll
                for (int rg = 0; rg < 4; ++rg)
                    vt[(hd * 24 + cc) * 72 + mt * 16 + qg * 4 + rg] = f2bf(acc[mt][rg]);
        }
    }
    __syncthreads();

    // ---------- phase 3: attention (wave-private row band, 4 heads serial) ----------
    const float scale = 0.20412414523193154f;  // 1/sqrt(24)
    #pragma unroll 1
    for (int hd = 0; hd < 4; ++hd) {
        // S = q @ k^T  (K=32, k cols 24..31 are zero)
        bf16x8 aq = *reinterpret_cast<const bf16x8*>(&qs[(wv * 16 + p) * 96 + hd * 24 + qg * 8]);
        f32x4 sacc[4];
        #pragma unroll
        for (int nt = 0; nt < 4; ++nt) {
            bf16x8 bk = *reinterpret_cast<const bf16x8*>(&ks[(nt * 16 + p) * 136 + hd * 32 + qg * 8]);
            sacc[nt] = MFMA16(aq, bk, fzero);
        }
        // row softmax: lane holds S[4qg+rg][16nt+p]; row lives across the 16-lane p-group
        float pw[4][4];
        float inv[4];
        #pragma unroll
        for (int rg = 0; rg < 4; ++rg) {
            float mm = fmaxf(fmaxf(sacc[0][rg], sacc[1][rg]), fmaxf(sacc[2][rg], sacc[3][rg]));
            mm = fmaxf(mm, __shfl_xor(mm, 1));
            mm = fmaxf(mm, __shfl_xor(mm, 2));
            mm = fmaxf(mm, __shfl_xor(mm, 4));
            mm = fmaxf(mm, __shfl_xor(mm, 8));
            float sum = 0.f;
            #pragma unroll
            for (int nt = 0; nt < 4; ++nt) {
                float e = __expf((sacc[nt][rg] - mm) * scale);
                pw[nt][rg] = e;
                sum += e;
            }
            sum += __shfl_xor(sum, 1);
            sum += __shfl_xor(sum, 2);
            sum += __shfl_xor(sum, 4);
            sum += __shfl_xor(sum, 8);
            inv[rg] = 1.0f / sum;
        }
        #pragma unroll
        for (int nt = 0; nt < 4; ++nt)
            #pragma unroll
            for (int rg = 0; rg < 4; ++rg)
                ps[(wv * 16 + qg * 4 + rg) * 72 + nt * 16 + p] = f2bf(pw[nt][rg] * inv[rg]);

        // O = P @ v  (M=16 band, N=24 (padded reads), K=64)
        f32x4 oacc[2];
        oacc[0] = fzero; oacc[1] = fzero;
        #pragma unroll
        for (int kt = 0; kt < 2; ++kt) {
            bf16x8 ap = *reinterpret_cast<const bf16x8*>(&ps[(wv * 16 + p) * 72 + kt * 32 + qg * 8]);
            #pragma unroll
            for (int n2 = 0; n2 < 2; ++n2) {
                bf16x8 bv = *reinterpret_cast<const bf16x8*>(&vt[(hd * 24 + n2 * 16 + p) * 72 + kt * 32 + qg * 8]);
                oacc[n2] = MFMA16(ap, bv, oacc[n2]);
            }
        }
        #pragma unroll
        for (int n2 = 0; n2 < 2; ++n2) {
            int cc = n2 * 16 + p;
            if (cc < 24) {
                #pragma unroll
                for (int rg = 0; rg < 4; ++rg)
                    xs[(wv * 16 + qg * 4 + rg) * 96 + hd * 24 + cc] = f2bf(oacc[n2][rg]);
            }
        }
    }

    // ---------- phase 4: proj + bias + scatter (reads only own rows of xs -> no barrier) ----------
    bf16x8 ofr[3];
    #pragma unroll
    for (int kt = 0; kt < 3; ++kt)
        ofr[kt] = *reinterpret_cast<const bf16x8*>(&xs[(wv * 16 + p) * 96 + kt * 32 + qg * 8]);
    const unsigned short* wpT = wsT + WQT_ELEMS;
    int obase = (((n_i * 4 + wv) * 64 + (m_i * 4 + qg)) * 128 + l_i * 4) * 96;
    #pragma unroll
    for (int nt = 0; nt < 6; ++nt) {
        f32x4 acc = fzero;
        #pragma unroll
        for (int kt = 0; kt < 3; ++kt) {
            bf16x8 bfr = *reinterpret_cast<const bf16x8*>(&wpT[(nt * 16 + p) * 96 + kt * 32 + qg * 8]);
            acc = MFMA16(ofr[kt], bfr, acc);
        }
        float bias = bproj[nt * 16 + p];
        #pragma unroll
        for (int rg = 0; rg < 4; ++rg)
            out[obase + rg * 96 + nt * 16 + p] = acc[rg] + bias;
    }
}

extern "C" void kernel_launch(void* const* d_in, const int* in_sizes, int n_in,
                              void* d_out, int out_size, void* d_ws, size_t ws_size,
                              hipStream_t stream) {
    const float* x     = (const float*)d_in[0];
    const float* wqkv  = (const float*)d_in[1];
    const float* wproj = (const float*)d_in[2];
    const float* bproj = (const float*)d_in[3];
    float* out = (float*)d_out;
    unsigned short* wsT = (unsigned short*)d_ws;

    wconv_kernel<<<dim3((WQT_ELEMS + WPT_ELEMS) / 256), dim3(256), 0, stream>>>(wqkv, wproj, wsT);
    winattn_kernel<<<dim3(4096), dim3(256), 0, stream>>>(x, wsT, bproj, out);
}

// Round 2
// 87.857 us; speedup vs baseline: 1.2312x; 1.2312x over previous
//
#include <hip/hip_runtime.h>
#include <hip/hip_bf16.h>

typedef __attribute__((ext_vector_type(8))) short bf16x8;
typedef __attribute__((ext_vector_type(4))) float f32x4;
typedef __attribute__((ext_vector_type(4))) unsigned short u16x4;
typedef __attribute__((ext_vector_type(4))) unsigned int u32x4;

#define MFMA16(a, b, c) __builtin_amdgcn_mfma_f32_16x16x32_bf16((a), (b), (c), 0, 0, 0)

#define WQT_ELEMS 27648   // 288*96
#define WPT_ELEMS 9216    // 96*96

__device__ __forceinline__ unsigned short f2bf(float f) {
    union { float f; unsigned u; } v; v.f = f;
    return (unsigned short)((v.u + 0x7FFFu + ((v.u >> 16) & 1u)) >> 16);
}
__device__ __forceinline__ unsigned pack2bf(float a, float b) {
    return (unsigned)f2bf(a) | ((unsigned)f2bf(b) << 16);
}

// Transpose+convert weights: wqT[j][c] = w_qkv[c][j] (bf16), wpT[j][c] = w_proj[c][j]
__global__ void wconv_kernel(const float* __restrict__ wqkv,
                             const float* __restrict__ wproj,
                             unsigned short* __restrict__ wsT) {
    int o = blockIdx.x * 256 + threadIdx.x;
    if (o < WQT_ELEMS) {
        int j = o / 96, c = o % 96;
        wsT[o] = f2bf(wqkv[c * 288 + j]);
    } else if (o < WQT_ELEMS + WPT_ELEMS) {
        int o2 = o - WQT_ELEMS;
        int j = o2 / 96, c = o2 % 96;
        wsT[o] = f2bf(wproj[c * 96 + j]);
    }
}

// One block per window. 256 threads = 4 waves. Wave wv owns token rows [16wv,16wv+16).
// LDS ~53 KB -> 3 blocks/CU.
__global__ __launch_bounds__(256, 3)
void winattn_kernel(const float* __restrict__ x,
                    const unsigned short* __restrict__ wsT,
                    const float* __restrict__ bproj,
                    float* __restrict__ out) {
    __shared__ __align__(16) unsigned short xs[64 * 96];      // 12288 B: x window; later O
    __shared__ __align__(16) unsigned short qs[64 * 96 + 8];  // 12304 B: q (pre-scaled), +8 zero pad
    __shared__ __align__(16) unsigned short ks[64 * 128];     // 16384 B: k, XOR-swizzled, head-padded K=32
    __shared__ __align__(16) unsigned short vt[96 * 64];      // 12288 B: v^T [c][t], XOR-swizzled

    char* ksb = (char*)ks;
    char* vtb = (char*)vt;

    const int tid = threadIdx.x;
    const int lane = tid & 63;
    const int wv = tid >> 6;
    const int p  = lane & 15;
    const int qg = lane >> 4;

    const int iw  = blockIdx.x;
    const int l_i = iw & 31;
    const int m_i = (iw >> 5) & 15;
    const int n_i = iw >> 9;

    const f32x4 fzero = {0.f, 0.f, 0.f, 0.f};
    const float qscale = 0.2944889313f;   // (1/sqrt(24)) * log2(e)

    // ---------- phase 1: stage x window -> LDS (bf16) ----------
    #pragma unroll
    for (int it = 0; it < 6; ++it) {
        int slot = tid + it * 256;            // 64 tokens * 24 float4 slots
        int t = slot / 24, cq = slot % 24;
        int td = t >> 4, th = (t >> 2) & 3, tw = t & 3;
        int off = (((n_i * 4 + td) * 64 + (m_i * 4 + th)) * 128 + (l_i * 4 + tw)) * 96 + cq * 4;
        float4 v4 = *reinterpret_cast<const float4*>(x + off);
        u16x4 h;
        h[0] = f2bf(v4.x); h[1] = f2bf(v4.y); h[2] = f2bf(v4.z); h[3] = f2bf(v4.w);
        *reinterpret_cast<u16x4*>(&xs[t * 96 + cq * 4]) = h;
    }
    // zero k head-pads (kk 24..31 per head, swizzled addr) and qs tail pad
    {
        int t = tid >> 2, hd = tid & 3;
        bf16x8 z = {0, 0, 0, 0, 0, 0, 0, 0};
        int cb = hd * 64 + 48;
        *reinterpret_cast<bf16x8*>(ksb + t * 256 + (cb ^ ((t & 7) << 4))) = z;
    }
    if (tid < 8) qs[64 * 96 + tid] = 0;
    __syncthreads();

    // ---------- phase 2: QKV GEMM  qkv[64][288] = xs[64][96] @ wq[96][288] ----------
    bf16x8 afr[4][3];
    #pragma unroll
    for (int mt = 0; mt < 4; ++mt)
        #pragma unroll
        for (int kt = 0; kt < 3; ++kt)
            afr[mt][kt] = *reinterpret_cast<const bf16x8*>(&xs[(mt * 16 + p) * 96 + kt * 32 + qg * 8]);

    auto do_tile = [&](int nt) {
        f32x4 acc[4] = {fzero, fzero, fzero, fzero};
        #pragma unroll
        for (int kt = 0; kt < 3; ++kt) {
            bf16x8 bfr = *reinterpret_cast<const bf16x8*>(&wsT[(nt * 16 + p) * 96 + kt * 32 + qg * 8]);
            #pragma unroll
            for (int mt = 0; mt < 4; ++mt)
                acc[mt] = MFMA16(afr[mt][kt], bfr, acc[mt]);
        }
        int jcol = nt * 16 + p;               // D: col = lane&15, row = qg*4+rg (+16mt)
        if (jcol < 96) {                      // q (pre-scaled by qscale)
            #pragma unroll
            for (int mt = 0; mt < 4; ++mt)
                #pragma unroll
                for (int rg = 0; rg < 4; ++rg)
                    qs[(mt * 16 + qg * 4 + rg) * 96 + jcol] = f2bf(acc[mt][rg] * qscale);
        } else if (jcol < 192) {              // k, swizzled
            int jk = jcol - 96;
            int hd = jk / 24, kk = jk % 24;
            int cb = hd * 64 + kk * 2;
            #pragma unroll
            for (int mt = 0; mt < 4; ++mt)
                #pragma unroll
                for (int rg = 0; rg < 4; ++rg) {
                    int t = mt * 16 + qg * 4 + rg;
                    *reinterpret_cast<unsigned short*>(ksb + t * 256 + (cb ^ ((t & 7) << 4))) = f2bf(acc[mt][rg]);
                }
        } else {                              // v^T, swizzled
            int jv = jcol - 192;
            int hd = jv / 24, cc = jv % 24;
            int vr = hd * 24 + cc;
            int rb = vr * 128, sw = (vr & 7) << 4;
            #pragma unroll
            for (int mt = 0; mt < 4; ++mt)
                #pragma unroll
                for (int rg = 0; rg < 4; ++rg) {
                    int u = mt * 16 + qg * 4 + rg;
                    *reinterpret_cast<unsigned short*>(vtb + rb + ((u * 2) ^ sw)) = f2bf(acc[mt][rg]);
                }
        }
    };
    // tiles: wv0: 0-4, wv1: 5-9, wv2: 10-13, wv3: 14-17 (compile-time trip counts)
    int base = (wv < 2) ? wv * 5 : 10 + (wv - 2) * 4;
    #pragma unroll
    for (int i = 0; i < 4; ++i) do_tile(base + i);
    if (wv < 2) do_tile(base + 4);
    __syncthreads();

    // ---------- phase 3: attention, swapped QK^T -> register softmax ----------
    #pragma unroll 1
    for (int hd = 0; hd < 4; ++hd) {
        // S^T = mfma(K, Q): D[col=q-token(p), row=k-token(qg*4+rg)+16nt]
        bf16x8 aqh = *reinterpret_cast<const bf16x8*>(&qs[(wv * 16 + p) * 96 + hd * 24 + qg * 8]);
        f32x4 sacc[4];
        #pragma unroll
        for (int nt = 0; nt < 4; ++nt) {
            int t = nt * 16 + p;
            bf16x8 ak = *reinterpret_cast<const bf16x8*>(ksb + t * 256 + ((hd * 64 + qg * 16) ^ ((t & 7) << 4)));
            sacc[nt] = MFMA16(ak, aqh, fzero);
        }
        // lane (p,qg) holds S[k = 16nt+4qg+rg][q = wv*16+p] (already *scale*log2e via q)
        float mm = sacc[0][0];
        #pragma unroll
        for (int nt = 0; nt < 4; ++nt)
            #pragma unroll
            for (int rg = 0; rg < 4; ++rg)
                mm = fmaxf(mm, sacc[nt][rg]);
        mm = fmaxf(mm, __shfl_xor(mm, 16));
        mm = fmaxf(mm, __shfl_xor(mm, 32));
        float pw[4][4];
        float sum = 0.f;
        #pragma unroll
        for (int nt = 0; nt < 4; ++nt)
            #pragma unroll
            for (int rg = 0; rg < 4; ++rg) {
                float e = exp2f(sacc[nt][rg] - mm);
                pw[nt][rg] = e;
                sum += e;
            }
        sum += __shfl_xor(sum, 16);
        sum += __shfl_xor(sum, 32);
        float inv = 1.0f / sum;
        unsigned pk[4][2];
        #pragma unroll
        for (int nt = 0; nt < 4; ++nt) {
            pk[nt][0] = pack2bf(pw[nt][0] * inv, pw[nt][1] * inv);
            pk[nt][1] = pack2bf(pw[nt][2] * inv, pw[nt][3] * inv);
        }
        // redistribute P to PV A-fragment layout: lane (p,qg) kt-chunk needs
        // P[k = kt*32+qg*8+j][q=p]; source lane (p, 2(qg&1)+(d>>1)), reg pk[2kt+(qg>>1)][d&1]
        u32x4 pa0, pa1;
        #pragma unroll
        for (int d = 0; d < 4; ++d) {
            int src = ((qg & 1) * 2 + (d >> 1)) * 16 + p;
            int lo0 = __shfl((int)pk[0][d & 1], src);
            int hi0 = __shfl((int)pk[1][d & 1], src);
            int lo1 = __shfl((int)pk[2][d & 1], src);
            int hi1 = __shfl((int)pk[3][d & 1], src);
            pa0[d] = (qg < 2) ? (unsigned)lo0 : (unsigned)hi0;
            pa1[d] = (qg < 2) ? (unsigned)lo1 : (unsigned)hi1;
        }
        bf16x8 a0 = __builtin_bit_cast(bf16x8, pa0);
        bf16x8 a1 = __builtin_bit_cast(bf16x8, pa1);
        // O = P @ v^T tiles
        f32x4 oacc[2] = {fzero, fzero};
        #pragma unroll
        for (int n2 = 0; n2 < 2; ++n2) {
            int vr = hd * 24 + n2 * 16 + p;
            vr = vr > 95 ? 95 : vr;           // clamp: cc>=24 lanes discarded anyway
            int rb = vr * 128, sw = (vr & 7) << 4;
            bf16x8 bv0 = *reinterpret_cast<const bf16x8*>(vtb + rb + ((qg * 16) ^ sw));
            bf16x8 bv1 = *reinterpret_cast<const bf16x8*>(vtb + rb + ((64 + qg * 16) ^ sw));
            oacc[n2] = MFMA16(a0, bv0, oacc[n2]);
            oacc[n2] = MFMA16(a1, bv1, oacc[n2]);
        }
        #pragma unroll
        for (int n2 = 0; n2 < 2; ++n2) {
            int cc = n2 * 16 + p;
            if (cc < 24) {
                #pragma unroll
                for (int rg = 0; rg < 4; ++rg)
                    xs[(wv * 16 + qg * 4 + rg) * 96 + hd * 24 + cc] = f2bf(oacc[n2][rg]);
            }
        }
    }

    // ---------- phase 4: proj + bias + scatter (own rows only -> no barrier) ----------
    bf16x8 ofr[3];
    #pragma unroll
    for (int kt = 0; kt < 3; ++kt)
        ofr[kt] = *reinterpret_cast<const bf16x8*>(&xs[(wv * 16 + p) * 96 + kt * 32 + qg * 8]);
    const unsigned short* wpT = wsT + WQT_ELEMS;
    int obase = (((n_i * 4 + wv) * 64 + (m_i * 4 + qg)) * 128 + l_i * 4) * 96;
    #pragma unroll
    for (int nt = 0; nt < 6; ++nt) {
        f32x4 acc = fzero;
        #pragma unroll
        for (int kt = 0; kt < 3; ++kt) {
            bf16x8 bfr = *reinterpret_cast<const bf16x8*>(&wpT[(nt * 16 + p) * 96 + kt * 32 + qg * 8]);
            acc = MFMA16(ofr[kt], bfr, acc);
        }
        float bias = bproj[nt * 16 + p];
        #pragma unroll
        for (int rg = 0; rg < 4; ++rg)
            out[obase + rg * 96 + nt * 16 + p] = acc[rg] + bias;
    }
}

extern "C" void kernel_launch(void* const* d_in, const int* in_sizes, int n_in,
                              void* d_out, int out_size, void* d_ws, size_t ws_size,
                              hipStream_t stream) {
    const float* x     = (const float*)d_in[0];
    const float* wqkv  = (const float*)d_in[1];
    const float* wproj = (const float*)d_in[2];
    const float* bproj = (const float*)d_in[3];
    float* out = (float*)d_out;
    unsigned short* wsT = (unsigned short*)d_ws;

    wconv_kernel<<<dim3((WQT_ELEMS + WPT_ELEMS) / 256), dim3(256), 0, stream>>>(wqkv, wproj, wsT);
    winattn_kernel<<<dim3(4096), dim3(256), 0, stream>>>(x, wsT, bproj, out);
}